// Round 2
// baseline (209.028 us; speedup 1.0000x reference)
//
#include <hip/hip_runtime.h>
#include <math.h>

// Problem constants (CosineWeights): B=32, H=8, J=8192, K=128, fp32.
constexpr int B_ = 32;
constexpr int H_ = 8;
constexpr int J_ = 8192;
constexpr int K_ = 128;
constexpr float EPS_ = 1e-6f;

constexpr int SBLK = 64;          // j-blocks per batch i
constexpr int JPB  = J_ / SBLK;   // 128 rows per block
constexpr int ITERS = JPB / 16;   // 16 rows per block-iteration (4 waves x 4 groups)

// ---------------- DPP reduction helpers (all-VALU, no LDS pipe) ----------------
template <int CTRL>
__device__ __forceinline__ float dpp_add(float x) {
  int v = __builtin_amdgcn_update_dpp(0, __float_as_int(x), CTRL, 0xF, 0xF, true);
  return x + __int_as_float(v);
}

// Sum across each 16-lane group; result in all 16 lanes.
__device__ __forceinline__ float red16(float x) {
  x = dpp_add<0xB1>(x);   // quad_perm [1,0,3,2]  (xor 1)
  x = dpp_add<0x4E>(x);   // quad_perm [2,3,0,1]  (xor 2)
  x = dpp_add<0x141>(x);  // row_half_mirror      (xor 4)
  x = dpp_add<0x140>(x);  // row_mirror           (xor 8)
  return x;
}

__device__ __forceinline__ float dot4f(const float4 a, const float4 b, float acc) {
  acc = fmaf(a.x, b.x, acc);
  acc = fmaf(a.y, b.y, acc);
  acc = fmaf(a.z, b.z, acc);
  acc = fmaf(a.w, b.w, acc);
  return acc;
}

// ---------------- Kernel 1: fused coeffs + 8-head projection + norm + sharpen --
// NO workspace: coefficients (mask^2*keys, mask^2), key norms, and
// softplus(strengths) are computed per-block from the raw inputs.
// Layout: 16 lanes per memory row, each lane owns float4 chunks {sub, sub+16}.
// Wave = 4 rows. Block = 256 threads = 16 rows per iteration, ITERS iterations.
__global__ __launch_bounds__(256, 2) void cw_main(
    const float* __restrict__ memory, const float* __restrict__ keys,
    const float* __restrict__ strengths, const float* __restrict__ mask,
    float* __restrict__ out)
{
  const int bid  = blockIdx.x;
  const int i    = bid / SBLK;
  const int jb   = bid % SBLK;
  const int t    = threadIdx.x;
  const int wave = t >> 6;
  const int lane = t & 63;
  const int grp  = lane >> 4;   // 0..3 (row within wave)
  const int sub  = lane & 15;   // 0..15 (k position)
  const int myh  = sub & 7;     // head this lane finalizes (for sub<8)

  // ---- Per-block coefficient build (amortized over 128 rows) ----
  const float4* keyv = (const float4*)(keys + (size_t)i * H_ * K_);
  const float4* mskv = (const float4*)(mask + (size_t)i * H_ * K_);
  float4 cA[H_][2];   // mask^2 * keys
  float4 cB[H_][2];   // mask^2
  float kn[H_];       // ||mask*keys||^2 partials -> full
  #pragma unroll
  for (int h = 0; h < H_; ++h) {
    float knp = 0.0f;
    #pragma unroll
    for (int c = 0; c < 2; ++c) {
      const float4 kv = keyv[h * 32 + c * 16 + sub];
      const float4 mv = mskv[h * 32 + c * 16 + sub];
      float4 b, a;
      b.x = mv.x * mv.x; b.y = mv.y * mv.y; b.z = mv.z * mv.z; b.w = mv.w * mv.w;
      a.x = b.x * kv.x;  a.y = b.y * kv.y;  a.z = b.z * kv.z;  a.w = b.w * kv.w;
      cB[h][c] = b;
      cA[h][c] = a;
      knp = dot4f(a, kv, knp);   // m^2 * k^2
    }
    kn[h] = red16(knp);
  }
  // Select this lane's head values (wave-uniform unrolled cndmask chain).
  float kn2 = kn[0];
  #pragma unroll
  for (int h = 1; h < H_; ++h) if (myh == h) kn2 = kn[h];
  const float knorm = sqrtf(kn2);
  const float st = strengths[i * H_ + myh];
  const float sp = fmaxf(st, 0.0f) + log1pf(expf(-fabsf(st)));  // softplus

  // ---- Stream memory rows ----
  const int j0 = jb * JPB + wave * 4 + grp;        // this thread's row at it=0
  const float4* rowv = (const float4*)(memory + ((size_t)i * J_ + j0) * K_);
  // 16 rows per iteration -> advance 16*K_/4 = 512 float4 per it.

  float4 m0 = rowv[sub];
  float4 m1 = rowv[sub + 16];

  #pragma unroll 1
  for (int it = 0; it < ITERS; ++it) {
    // Branchless, always-in-bounds prefetch (last iter re-reads row 0).
    const int nx = (it + 1 < ITERS) ? (it + 1) : 0;
    const float4* nr = rowv + (size_t)nx * 512;
    const float4 n0v = nr[sub];
    const float4 n1v = nr[sub + 16];

    float4 sq0, sq1;
    sq0.x = m0.x * m0.x; sq0.y = m0.y * m0.y; sq0.z = m0.z * m0.z; sq0.w = m0.w * m0.w;
    sq1.x = m1.x * m1.x; sq1.y = m1.y * m1.y; sq1.z = m1.z * m1.z; sq1.w = m1.w * m1.w;

    float p[H_], nn[H_];
    #pragma unroll
    for (int h = 0; h < H_; ++h) {
      float a = m0.x * cA[h][0].x;
      a = fmaf(m0.y, cA[h][0].y, a);
      a = fmaf(m0.z, cA[h][0].z, a);
      a = fmaf(m0.w, cA[h][0].w, a);
      a = dot4f(m1, cA[h][1], a);
      p[h] = a;
      float b = sq0.x * cB[h][0].x;
      b = fmaf(sq0.y, cB[h][0].y, b);
      b = fmaf(sq0.z, cB[h][0].z, b);
      b = fmaf(sq0.w, cB[h][0].w, b);
      b = dot4f(sq1, cB[h][1], b);
      nn[h] = b;
    }

    // 16 independent 16-lane reductions, all DPP.
    #pragma unroll
    for (int h = 0; h < H_; ++h) {
      p[h]  = red16(p[h]);
      nn[h] = red16(nn[h]);
    }

    if (sub < 8) {
      float pp = p[0], qq = nn[0];
      #pragma unroll
      for (int h = 1; h < H_; ++h) {
        if (myh == h) { pp = p[h]; qq = nn[h]; }
      }
      const float mnorm = sqrtf(qq);
      const float sharp = pp / (knorm * mnorm + EPS_) * sp;
      const int j = jb * JPB + it * 16 + wave * 4 + grp;
      out[((size_t)(i * H_ + myh)) * J_ + j] = sharp;
    }

    m0 = n0v;
    m1 = n1v;
  }
}

// ---------------- Kernel 2: in-place softmax over J per (i,h) row ----------------
__global__ __launch_bounds__(256) void cw_softmax(float* __restrict__ out)
{
  const int row = blockIdx.x;   // 0..255
  float4* pv = (float4*)(out + (size_t)row * J_);
  const int t = threadIdx.x;
  const int wave = t >> 6, lane = t & 63;

  float4 v[8];
  float mx = -3.4e38f;
  #pragma unroll
  for (int c = 0; c < 8; ++c) {
    v[c] = pv[t + c * 256];
    mx = fmaxf(mx, fmaxf(fmaxf(v[c].x, v[c].y), fmaxf(v[c].z, v[c].w)));
  }
  #pragma unroll
  for (int o = 32; o > 0; o >>= 1) mx = fmaxf(mx, __shfl_xor(mx, o, 64));
  __shared__ float sm[4];
  __shared__ float ss[4];
  if (lane == 0) sm[wave] = mx;
  __syncthreads();
  mx = fmaxf(fmaxf(sm[0], sm[1]), fmaxf(sm[2], sm[3]));

  float sum = 0.0f;
  #pragma unroll
  for (int c = 0; c < 8; ++c) {
    v[c].x = expf(v[c].x - mx);
    v[c].y = expf(v[c].y - mx);
    v[c].z = expf(v[c].z - mx);
    v[c].w = expf(v[c].w - mx);
    sum += (v[c].x + v[c].y) + (v[c].z + v[c].w);
  }
  #pragma unroll
  for (int o = 32; o > 0; o >>= 1) sum += __shfl_xor(sum, o, 64);
  if (lane == 0) ss[wave] = sum;
  __syncthreads();
  sum = (ss[0] + ss[1]) + (ss[2] + ss[3]);
  const float inv = 1.0f / sum;

  #pragma unroll
  for (int c = 0; c < 8; ++c) {
    v[c].x *= inv; v[c].y *= inv; v[c].z *= inv; v[c].w *= inv;
    pv[t + c * 256] = v[c];
  }
}

extern "C" void kernel_launch(void* const* d_in, const int* in_sizes, int n_in,
                              void* d_out, int out_size, void* d_ws, size_t ws_size,
                              hipStream_t stream) {
  const float* memory    = (const float*)d_in[0];  // [B,J,K]
  const float* keys      = (const float*)d_in[1];  // [B,H,K]
  const float* strengths = (const float*)d_in[2];  // [B,H,1]
  const float* mask      = (const float*)d_in[3];  // [B,H,K]
  float* out = (float*)d_out;                      // [B,H,J]

  // NOTE: d_ws intentionally unused — all coefficients computed in-kernel.
  (void)d_ws; (void)ws_size;

  cw_main<<<B_ * SBLK, 256, 0, stream>>>(memory, keys, strengths, mask, out);
  cw_softmax<<<B_ * H_, 256, 0, stream>>>(out);
}

// Round 3
// 205.807 us; speedup vs baseline: 1.0157x; 1.0157x over previous
//
#include <hip/hip_runtime.h>
#include <math.h>

// Problem constants (CosineWeights): B=32, H=8, J=8192, K=128, fp32.
constexpr int B_ = 32;
constexpr int H_ = 8;
constexpr int J_ = 8192;
constexpr int K_ = 128;
constexpr float EPS_ = 1e-6f;

constexpr int SBLK = 64;          // j-blocks per batch i
constexpr int JPB  = J_ / SBLK;   // 128 rows per block
constexpr int RPI  = 8;           // rows per block-iteration (2 wave-pairs x 4 groups)
constexpr int ITERS = JPB / RPI;  // 16

// ---------------- DPP reduction helpers (all-VALU, no LDS pipe) ----------------
template <int CTRL>
__device__ __forceinline__ float dpp_add(float x) {
  int v = __builtin_amdgcn_update_dpp(0, __float_as_int(x), CTRL, 0xF, 0xF, true);
  return x + __int_as_float(v);
}

// Sum across each 16-lane group; result in all 16 lanes.
__device__ __forceinline__ float red16(float x) {
  x = dpp_add<0xB1>(x);   // quad_perm [1,0,3,2]  (xor 1)
  x = dpp_add<0x4E>(x);   // quad_perm [2,3,0,1]  (xor 2)
  x = dpp_add<0x141>(x);  // row_half_mirror      (xor 4)
  x = dpp_add<0x140>(x);  // row_mirror           (xor 8)
  return x;
}

__device__ __forceinline__ float dot4f(const float4 a, const float4 b, float acc) {
  acc = fmaf(a.x, b.x, acc);
  acc = fmaf(a.y, b.y, acc);
  acc = fmaf(a.z, b.z, acc);
  acc = fmaf(a.w, b.w, acc);
  return acc;
}

// ---------------- Kernel 1: fused coeffs + projection + norm + sharpen --------
// Head-split layout: waves 0-1 compute heads 0-3, waves 2-3 heads 4-7.
// Sibling waves (0,2) and (1,3) stream the SAME memory rows (duplicate loads
// hit L1/L2; HBM fetch unchanged) — halves coefficient VGPRs (128 -> 64) so
// occupancy doubles (2 -> 4 waves/SIMD).
// Within a wave: 4 groups of 16 lanes; each group owns one row per iteration;
// lane sub owns float4 k-chunks {sub, sub+16}.
__global__ __launch_bounds__(256, 4) void cw_main(
    const float* __restrict__ memory, const float* __restrict__ keys,
    const float* __restrict__ strengths, const float* __restrict__ mask,
    float* __restrict__ out)
{
  const int bid  = blockIdx.x;
  const int i    = bid >> 6;     // / SBLK
  const int jb   = bid & 63;     // % SBLK
  const int t    = threadIdx.x;
  const int wave = t >> 6;
  const int lane = t & 63;
  const int grp  = lane >> 4;    // 0..3 (row within wave)
  const int sub  = lane & 15;    // 0..15 (k position)
  const int hs   = (wave >> 1) << 2;  // head-set base: 0 or 4
  const int hl   = sub & 3;           // local head this lane finalizes
  const int myh  = hs + hl;

  // ---- Per-block coefficient build (amortized over 128 rows) ----
  const float4* keyv = (const float4*)(keys + (size_t)i * H_ * K_);
  const float4* mskv = (const float4*)(mask + (size_t)i * H_ * K_);
  float4 cA[4][2];   // mask^2 * keys   (this wave's 4 heads)
  float4 cB[4][2];   // mask^2
  float kn[4];       // ||mask*keys||^2
  #pragma unroll
  for (int hh = 0; hh < 4; ++hh) {
    const int h = hs + hh;
    float knp = 0.0f;
    #pragma unroll
    for (int c = 0; c < 2; ++c) {
      const float4 kv = keyv[h * 32 + c * 16 + sub];
      const float4 mv = mskv[h * 32 + c * 16 + sub];
      float4 b, a;
      b.x = mv.x * mv.x; b.y = mv.y * mv.y; b.z = mv.z * mv.z; b.w = mv.w * mv.w;
      a.x = b.x * kv.x;  a.y = b.y * kv.y;  a.z = b.z * kv.z;  a.w = b.w * kv.w;
      cB[hh][c] = b;
      cA[hh][c] = a;
      knp = dot4f(a, kv, knp);   // m^2 * k^2
    }
    kn[hh] = red16(knp);
  }
  float kn2 = kn[0];
  #pragma unroll
  for (int hh = 1; hh < 4; ++hh) if (hl == hh) kn2 = kn[hh];
  const float knorm = sqrtf(kn2);
  const float st = strengths[i * H_ + myh];
  const float sp = fmaxf(st, 0.0f) + log1pf(expf(-fabsf(st)));  // softplus

  // ---- Stream memory rows ----
  const int jrow0 = (wave & 1) * 4 + grp;          // row offset within iteration
  const int j0    = jb * JPB + jrow0;
  const float4* rowv = (const float4*)(memory + ((size_t)i * J_ + j0) * K_);
  // RPI rows per iteration -> advance RPI*K_/4 = 256 float4 per it.

  float4 m0 = rowv[sub];
  float4 m1 = rowv[sub + 16];

  #pragma unroll 1
  for (int it = 0; it < ITERS; ++it) {
    // Branchless, always-in-bounds prefetch (last iter re-reads row 0).
    const int nx = (it + 1 < ITERS) ? (it + 1) : 0;
    const float4* nr = rowv + (size_t)nx * 256;
    const float4 n0v = nr[sub];
    const float4 n1v = nr[sub + 16];

    float4 sq0, sq1;
    sq0.x = m0.x * m0.x; sq0.y = m0.y * m0.y; sq0.z = m0.z * m0.z; sq0.w = m0.w * m0.w;
    sq1.x = m1.x * m1.x; sq1.y = m1.y * m1.y; sq1.z = m1.z * m1.z; sq1.w = m1.w * m1.w;

    float p[4], nn[4];
    #pragma unroll
    for (int hh = 0; hh < 4; ++hh) {
      float a = m0.x * cA[hh][0].x;
      a = fmaf(m0.y, cA[hh][0].y, a);
      a = fmaf(m0.z, cA[hh][0].z, a);
      a = fmaf(m0.w, cA[hh][0].w, a);
      a = dot4f(m1, cA[hh][1], a);
      p[hh] = a;
      float b = sq0.x * cB[hh][0].x;
      b = fmaf(sq0.y, cB[hh][0].y, b);
      b = fmaf(sq0.z, cB[hh][0].z, b);
      b = fmaf(sq0.w, cB[hh][0].w, b);
      b = dot4f(sq1, cB[hh][1], b);
      nn[hh] = b;
    }

    // 8 independent 16-lane reductions, all DPP.
    #pragma unroll
    for (int hh = 0; hh < 4; ++hh) {
      p[hh]  = red16(p[hh]);
      nn[hh] = red16(nn[hh]);
    }

    if (sub < 4) {
      float pp = p[0], qq = nn[0];
      #pragma unroll
      for (int hh = 1; hh < 4; ++hh) {
        if (hl == hh) { pp = p[hh]; qq = nn[hh]; }
      }
      const float mnorm = sqrtf(qq);
      const float sharp = pp / (knorm * mnorm + EPS_) * sp;
      const int j = jb * JPB + it * RPI + jrow0;
      out[((size_t)(i * H_ + myh)) * J_ + j] = sharp;
    }

    m0 = n0v;
    m1 = n1v;
  }
}

// ---------------- Kernel 2: in-place softmax over J per (i,h) row ----------------
// 1024 threads/block (16 waves) for latency hiding; each thread owns 2 float4.
__global__ __launch_bounds__(1024) void cw_softmax(float* __restrict__ out)
{
  const int row = blockIdx.x;   // 0..255
  float4* pv = (float4*)(out + (size_t)row * J_);
  const int t = threadIdx.x;
  const int wave = t >> 6, lane = t & 63;

  float4 v0 = pv[t];
  float4 v1 = pv[t + 1024];
  float mx = fmaxf(fmaxf(fmaxf(v0.x, v0.y), fmaxf(v0.z, v0.w)),
                   fmaxf(fmaxf(v1.x, v1.y), fmaxf(v1.z, v1.w)));
  #pragma unroll
  for (int o = 32; o > 0; o >>= 1) mx = fmaxf(mx, __shfl_xor(mx, o, 64));
  __shared__ float sm[16];
  __shared__ float ss[16];
  if (lane == 0) sm[wave] = mx;
  __syncthreads();
  mx = sm[lane & 15];
  #pragma unroll
  for (int o = 8; o > 0; o >>= 1) mx = fmaxf(mx, __shfl_xor(mx, o, 64));

  v0.x = expf(v0.x - mx); v0.y = expf(v0.y - mx);
  v0.z = expf(v0.z - mx); v0.w = expf(v0.w - mx);
  v1.x = expf(v1.x - mx); v1.y = expf(v1.y - mx);
  v1.z = expf(v1.z - mx); v1.w = expf(v1.w - mx);
  float sum = ((v0.x + v0.y) + (v0.z + v0.w)) + ((v1.x + v1.y) + (v1.z + v1.w));
  #pragma unroll
  for (int o = 32; o > 0; o >>= 1) sum += __shfl_xor(sum, o, 64);
  if (lane == 0) ss[wave] = sum;
  __syncthreads();
  sum = ss[lane & 15];
  #pragma unroll
  for (int o = 8; o > 0; o >>= 1) sum += __shfl_xor(sum, o, 64);
  const float inv = 1.0f / sum;

  v0.x *= inv; v0.y *= inv; v0.z *= inv; v0.w *= inv;
  v1.x *= inv; v1.y *= inv; v1.z *= inv; v1.w *= inv;
  pv[t] = v0;
  pv[t + 1024] = v1;
}

extern "C" void kernel_launch(void* const* d_in, const int* in_sizes, int n_in,
                              void* d_out, int out_size, void* d_ws, size_t ws_size,
                              hipStream_t stream) {
  const float* memory    = (const float*)d_in[0];  // [B,J,K]
  const float* keys      = (const float*)d_in[1];  // [B,H,K]
  const float* strengths = (const float*)d_in[2];  // [B,H,1]
  const float* mask      = (const float*)d_in[3];  // [B,H,K]
  float* out = (float*)d_out;                      // [B,H,J]

  // NOTE: d_ws intentionally unused — all coefficients computed in-kernel.
  (void)d_ws; (void)ws_size;

  cw_main<<<B_ * SBLK, 256, 0, stream>>>(memory, keys, strengths, mask, out);
  cw_softmax<<<B_ * H_, 1024, 0, stream>>>(out);
}